// Round 1
// baseline (3877.465 us; speedup 1.0000x reference)
//
#include <hip/hip_runtime.h>
#include <hip/hip_bf16.h>
#include <cstddef>
#include <cstdint>

// ---------------------------------------------------------------------------
// Direct conv 3x3 stride 2, SAME padding (pad_lo=0, pad_hi=1 on both axes,
// verified: out=ceil(in/2), total_pad=1), NCHW, fused bias + ReLU.
// Block: 256 threads = 8 k-quads x 32 spatial threads.
// Block tile: 32 output channels x 8x8 spatial. Thread tile: 4 k x 1x2 spatial.
// Input tile (17x17 per channel, padded stride 20 for 8B-aligned float2 reads)
// and weights (padded to 12 floats for float4 reads) staged in LDS, CT channels
// per stage.
// ---------------------------------------------------------------------------
template<int C, int K, int IH, int IW, int OH, int OW, int CT>
__global__ __launch_bounds__(256) void conv3x3s2_relu(
    const float* __restrict__ in, const float* __restrict__ w,
    const float* __restrict__ bias, float* __restrict__ out) {
  constexpr int KT = 32;
  constexpr int TS = 8;
  constexpr int ITS = 17;
  constexpr int IPAD = 20;
  __shared__ __align__(16) float s_in[CT][ITS][IPAD];
  __shared__ __align__(16) float s_w[KT][CT][12];

  const int n = blockIdx.z;
  const int kb = blockIdx.y * KT;
  constexpr int TX = (OW + TS - 1) / TS;
  const int ty = blockIdx.x / TX, tx = blockIdx.x % TX;
  const int oy0 = ty * TS, ox0 = tx * TS;
  const int iy0 = oy0 * 2, ix0 = ox0 * 2;

  const int tid = threadIdx.x;
  const int kq = tid >> 5;   // 0..7, 4 output channels each
  const int st = tid & 31;
  const int sy = st >> 2;    // 0..7
  const int sx2 = st & 3;    // 0..3, two output cols each

  float acc[4][2];
  #pragma unroll
  for (int a = 0; a < 4; ++a) { acc[a][0] = 0.f; acc[a][1] = 0.f; }

  for (int c0 = 0; c0 < C; c0 += CT) {
    __syncthreads();
    // stage input tile (zero-pad out-of-range: SAME pad on bottom/right)
    for (int idx = tid; idx < CT * ITS * ITS; idx += 256) {
      int cc = idx / (ITS * ITS);
      int r = (idx / ITS) % ITS;
      int x = idx % ITS;
      int iy = iy0 + r, ix = ix0 + x;
      float v = 0.f;
      if (iy < IH && ix < IW)
        v = in[((size_t)(n * C + c0 + cc) * IH + iy) * IW + ix];
      s_in[cc][r][x] = v;
    }
    // stage weights [KT][CT][9] (OIHW, contiguous 9 taps per (k,c))
    for (int idx = tid; idx < KT * CT * 9; idx += 256) {
      int kk = idx / (CT * 9);
      int rem = idx % (CT * 9);
      int cc = rem / 9, tap = rem % 9;
      s_w[kk][cc][tap] = w[((size_t)(kb + kk) * C + c0 + cc) * 9 + tap];
    }
    __syncthreads();

    const int ly = sy * 2, lx = sx2 * 4;
    for (int cc = 0; cc < CT; ++cc) {
      float v[3][5];
      #pragma unroll
      for (int r = 0; r < 3; ++r) {
        const float* rp = &s_in[cc][ly + r][lx];   // 8B aligned (stride 20, lx even)
        float2 p0 = *(const float2*)rp;
        float2 p1 = *(const float2*)(rp + 2);
        v[r][0] = p0.x; v[r][1] = p0.y; v[r][2] = p1.x; v[r][3] = p1.y;
        v[r][4] = rp[4];
      }
      #pragma unroll
      for (int kk = 0; kk < 4; ++kk) {
        const float4* wp = (const float4*)&s_w[kq * 4 + kk][cc][0];  // 16B aligned
        float4 w0 = wp[0], w1 = wp[1];
        float w8 = s_w[kq * 4 + kk][cc][8];
        float wt[9] = {w0.x, w0.y, w0.z, w0.w, w1.x, w1.y, w1.z, w1.w, w8};
        #pragma unroll
        for (int r = 0; r < 3; ++r)
          #pragma unroll
          for (int x = 0; x < 3; ++x) {
            acc[kk][0] = fmaf(v[r][x],     wt[r * 3 + x], acc[kk][0]);
            acc[kk][1] = fmaf(v[r][x + 2], wt[r * 3 + x], acc[kk][1]);
          }
      }
    }
  }

  const int oy = oy0 + sy;
  if (oy < OH) {
    #pragma unroll
    for (int kk = 0; kk < 4; ++kk) {
      const int k = kb + kq * 4 + kk;
      const float bv = bias[k];
      #pragma unroll
      for (int xi = 0; xi < 2; ++xi) {
        const int ox = ox0 + sx2 * 2 + xi;
        if (ox < OW)
          out[((size_t)(n * K + k) * OH + oy) * OW + ox] = fmaxf(acc[kk][xi] + bv, 0.f);
      }
    }
  }
}

// ---------------------------------------------------------------------------
// Text branch: masked mean of embedding rows. One block per batch row.
// ---------------------------------------------------------------------------
__global__ __launch_bounds__(256) void embed_mean_kernel(
    const int* __restrict__ seq, const int* __restrict__ len,
    const float* __restrict__ emb, float* __restrict__ means) {
  const int b = blockIdx.x;
  const int L = len[b];            // in [1, 128]
  const int d = threadIdx.x;       // 256 threads, 2 dims each
  float a0 = 0.f, a1 = 0.f;
  for (int s = 0; s < L; ++s) {
    const float* e = emb + (size_t)seq[b * 128 + s] * 512;
    a0 += e[d];
    a1 += e[d + 256];
  }
  const float inv = 1.f / (float)L;
  means[b * 512 + d] = a0 * inv;
  means[b * 512 + d + 256] = a1 * inv;
}

// ---------------------------------------------------------------------------
// Global 14x14 avg pool: one wave per (n,k) row of 196 elements.
// Writes into feats[n][0..511] (ld 1024).
// ---------------------------------------------------------------------------
__global__ __launch_bounds__(256) void avgpool_kernel(
    const float* __restrict__ in, float* __restrict__ feats, int nrows) {
  const int gw = (blockIdx.x * 256 + threadIdx.x) >> 6;
  const int lane = threadIdx.x & 63;
  if (gw >= nrows) return;  // wave-uniform
  const float* p = in + (size_t)gw * 196;
  float s = p[lane] + p[lane + 64] + p[lane + 128] + ((lane < 4) ? p[lane + 192] : 0.f);
  #pragma unroll
  for (int o = 32; o > 0; o >>= 1) s += __shfl_down(s, o);
  if (lane == 0) {
    const int n = gw >> 9, k = gw & 511;
    feats[(size_t)n * 1024 + k] = s * (1.f / 196.f);
  }
}

// ---------------------------------------------------------------------------
// Small FC: out[m][col] = act(x[m] . W[:,col] + b[col]), W row-major [K][N].
// One block per (col-chunk, m); x row staged in LDS, W reads coalesced.
// ---------------------------------------------------------------------------
template<int K, int N, bool RELU>
__global__ __launch_bounds__(256) void fc_kernel(
    const float* __restrict__ x, int ldx,
    const float* __restrict__ w, const float* __restrict__ bias,
    float* __restrict__ out, int ldo) {
  __shared__ float row[K];
  const int m = blockIdx.y;
  for (int i = threadIdx.x; i < K; i += 256) row[i] = x[(size_t)m * ldx + i];
  __syncthreads();
  const int col = blockIdx.x * 256 + threadIdx.x;
  if (col < N) {
    float a = bias[col];
    for (int k = 0; k < K; ++k) a = fmaf(row[k], w[(size_t)k * N + col], a);
    out[(size_t)m * ldo + col] = RELU ? fmaxf(a, 0.f) : a;
  }
}

// ---------------------------------------------------------------------------
extern "C" void kernel_launch(void* const* d_in, const int* in_sizes, int n_in,
                              void* d_out, int out_size, void* d_ws, size_t ws_size,
                              hipStream_t stream) {
  const float* images = (const float*)d_in[0];
  const int*   seq    = (const int*)d_in[1];
  const int*   len    = (const int*)d_in[2];
  // d_in[3] = lengths_var (duplicate, unused)
  const float* emb    = (const float*)d_in[4];
  const float* cw1 = (const float*)d_in[5];  const float* cb1 = (const float*)d_in[6];
  const float* cw2 = (const float*)d_in[7];  const float* cb2 = (const float*)d_in[8];
  const float* cw3 = (const float*)d_in[9];  const float* cb3 = (const float*)d_in[10];
  const float* cw4 = (const float*)d_in[11]; const float* cb4 = (const float*)d_in[12];
  const float* rnn_w = (const float*)d_in[13]; const float* rnn_b = (const float*)d_in[14];
  const float* fc1_w = (const float*)d_in[15]; const float* fc1_b = (const float*)d_in[16];
  const float* fc2_w = (const float*)d_in[17]; const float* fc2_b = (const float*)d_in[18];
  const float* clf_w = (const float*)d_in[19]; const float* clf_b = (const float*)d_in[20];
  float* out = (float*)d_out;
  float* ws = (float*)d_ws;

  // Workspace layout (floats). Batch is processed in chunks if ws is small:
  // bufA holds act1 (64ch@112^2) then act3 (256ch@28^2); bufB act2 then act4.
  const size_t A_PER_N = (size_t)64 * 112 * 112;   // 802816
  const size_t B_PER_N = (size_t)128 * 56 * 56;    // 401408
  const size_t SMALL = 64 * 512 + 64 * 1024 + 64 * 512 + 64 * 512;
  const size_t wsf = ws_size / sizeof(float);
  int chunk = 64;
  if (wsf < SMALL + 64 * (A_PER_N + B_PER_N)) {
    size_t avail = (wsf > SMALL) ? (wsf - SMALL) : 0;
    size_t c = avail / (A_PER_N + B_PER_N);
    chunk = (c < 1) ? 1 : (c > 64 ? 64 : (int)c);
  }
  float* bufA  = ws;
  float* bufB  = bufA + (size_t)chunk * A_PER_N;
  float* means = bufB + (size_t)chunk * B_PER_N;
  float* feats = means + 64 * 512;
  float* h1    = feats + 64 * 1024;
  float* h2    = h1 + 64 * 512;

  // Text branch: masked mean -> sent = means @ rnn_w + rnn_b, into feats[:,512:]
  embed_mean_kernel<<<64, 256, 0, stream>>>(seq, len, emb, means);
  fc_kernel<512, 512, false><<<dim3(2, 64), 256, 0, stream>>>(
      means, 512, rnn_w, rnn_b, feats + 512, 1024);

  // Image branch
  for (int n0 = 0; n0 < 64; n0 += chunk) {
    int nb = 64 - n0; if (nb > chunk) nb = chunk;
    conv3x3s2_relu<3, 64, 224, 224, 112, 112, 3>
        <<<dim3(14 * 14, 64 / 32, nb), 256, 0, stream>>>(
            images + (size_t)n0 * 3 * 224 * 224, cw1, cb1, bufA);
    conv3x3s2_relu<64, 128, 112, 112, 56, 56, 16>
        <<<dim3(7 * 7, 128 / 32, nb), 256, 0, stream>>>(bufA, cw2, cb2, bufB);
    conv3x3s2_relu<128, 256, 56, 56, 28, 28, 16>
        <<<dim3(4 * 4, 256 / 32, nb), 256, 0, stream>>>(bufB, cw3, cb3, bufA);
    conv3x3s2_relu<256, 512, 28, 28, 14, 14, 16>
        <<<dim3(2 * 2, 512 / 32, nb), 256, 0, stream>>>(bufA, cw4, cb4, bufB);
    int nrows = nb * 512;
    avgpool_kernel<<<(nrows + 3) / 4, 256, 0, stream>>>(
        bufB, feats + (size_t)n0 * 1024, nrows);
  }

  // Head
  fc_kernel<1024, 512, true ><<<dim3(2, 64), 256, 0, stream>>>(feats, 1024, fc1_w, fc1_b, h1, 512);
  fc_kernel<512,  512, true ><<<dim3(2, 64), 256, 0, stream>>>(h1,    512,  fc2_w, fc2_b, h2, 512);
  fc_kernel<512, 1000, false><<<dim3(4, 64), 256, 0, stream>>>(h2,    512,  clf_w, clf_b, out, 1000);
}

// Round 2
// 524.221 us; speedup vs baseline: 7.3966x; 7.3966x over previous
//
#include <hip/hip_runtime.h>
#include <hip/hip_bf16.h>
#include <cstddef>
#include <cstdint>

typedef unsigned short u16;
typedef __attribute__((ext_vector_type(8))) short bf16x8;   // 8 bf16 in 4 VGPRs
typedef __attribute__((ext_vector_type(4))) float f32x4;
typedef __attribute__((ext_vector_type(8))) unsigned short u16x8;

static __device__ __forceinline__ u16 f2bf(float x) {       // RNE f32->bf16
  unsigned u = __float_as_uint(x);
  u += 0x7fffu + ((u >> 16) & 1u);
  return (u16)(u >> 16);
}
static __device__ __forceinline__ float bflo(unsigned u) { return __uint_as_float(u << 16); }
static __device__ __forceinline__ float bfhi(unsigned u) { return __uint_as_float(u & 0xffff0000u); }

// ---------------------------------------------------------------------------
// conv1: 3->64ch, 3x3 s2 SAME, fp32 NCHW in -> bf16 NHWC out. Direct VALU.
// Block 256 = 16x16 pixels; all 64 outch per thread; weights in LDS.
// ---------------------------------------------------------------------------
__global__ __launch_bounds__(256) void conv1_s2(
    const float* __restrict__ in,   // [n][3][224][224]
    const float* __restrict__ w,    // [64][3][3][3] OIHW
    const float* __restrict__ bias,
    u16* __restrict__ out) {        // [n][112][112][64]
  __shared__ float sw[64 * 27];
  __shared__ float sb[64];
  const int tid = threadIdx.x;
  if (tid < 64) sb[tid] = bias[tid];
  for (int i = tid; i < 64 * 27; i += 256) sw[i] = w[i];
  __syncthreads();
  const int n = blockIdx.y;
  const int by = blockIdx.x / 7, bx = blockIdx.x % 7;
  const int oy = by * 16 + (tid >> 4), ox = bx * 16 + (tid & 15);
  const float* ibase = in + (size_t)n * 3 * 224 * 224 + (size_t)(2 * oy) * 224 + 2 * ox;
  float v[27];
  #pragma unroll
  for (int c = 0; c < 3; ++c)
    #pragma unroll
    for (int r = 0; r < 3; ++r)
      #pragma unroll
      for (int s = 0; s < 3; ++s) {
        const int iy = 2 * oy + r, ix = 2 * ox + s;
        float x = 0.f;
        if (iy < 224 && ix < 224) x = ibase[(size_t)c * 224 * 224 + r * 224 + s];
        v[c * 9 + r * 3 + s] = x;
      }
  u16* obase = out + (((size_t)n * 112 + oy) * 112 + ox) * 64;
  #pragma unroll
  for (int kc = 0; kc < 8; ++kc) {
    u16x8 pack;
    #pragma unroll
    for (int k8 = 0; k8 < 8; ++k8) {
      const int k = kc * 8 + k8;
      float a = sb[k];
      const float* wk = &sw[k * 27];
      #pragma unroll
      for (int t = 0; t < 27; ++t) a = fmaf(v[t], wk[t], a);
      pack[k8] = f2bf(fmaxf(a, 0.f));
    }
    *(u16x8*)(obase + kc * 8) = pack;
  }
}

// ---------------------------------------------------------------------------
// Weight repack: OIHW fp32 [K][C][3][3] -> MFMA-fragment-ordered bf16:
//   pw[(((tap*CB + cb)*NB + nbg)*64 + lane)*8 + j] = W[nbg*16 + lane%16]
//        [cb*32 + (lane/16)*8 + j][tap/3][tap%3]
// so a B-fragment (B[c][n] = W[n][c][tap]) is one coalesced 16B/lane load.
// ---------------------------------------------------------------------------
template<int C, int K>
__global__ __launch_bounds__(256) void pack_w(const float* __restrict__ w,
                                              u16* __restrict__ pw) {
  constexpr int CB = C / 32, NB = K / 16;
  const int idx = blockIdx.x * 256 + threadIdx.x;
  if (idx >= 9 * C * K) return;
  const int j = idx & 7;
  const int L = (idx >> 3) & 63;
  int t = idx >> 9;
  const int nbg = t % NB; t /= NB;
  const int cb = t % CB;
  const int tap = t / CB;
  const int n = nbg * 16 + (L & 15);
  const int c = cb * 32 + ((L >> 4) << 3) + j;
  pw[idx] = f2bf(w[((size_t)n * C + c) * 9 + tap]);
}

// ---------------------------------------------------------------------------
// Implicit-GEMM 3x3 s2 SAME conv, bf16 NHWC in/out, fp32 accum, bias+ReLU.
// mfma_f32_16x16x32_bf16. Block 256 thr = 4 waves (2m x 2n); block tile
// 64 pixels x 128 outch; wave tile 32px x 64ch = 2x4 fragments.
// A-fragments load 16B/lane straight from NHWC global (channel-contiguous).
// ---------------------------------------------------------------------------
template<int C, int K, int OH, int OW>
__global__ __launch_bounds__(256) void conv3x3s2_mfma(
    const u16* __restrict__ in,   // [n][2*OH][2*OW][C] bf16
    const u16* __restrict__ pw,   // packed fragment weights
    const float* __restrict__ bias,
    u16* __restrict__ out) {      // [n][OH][OW][K] bf16
  constexpr int IH = 2 * OH, IW = 2 * OW;
  constexpr int P = OH * OW;
  constexpr int MB = (P + 63) / 64;
  constexpr int CB = C / 32, NB = K / 16;
  const int bm = blockIdx.x % MB;
  const int n = blockIdx.x / MB;
  const int nbh = blockIdx.y;                 // 128-ch group
  const int lane = threadIdx.x & 63, wv = threadIdx.x >> 6;
  const int mh = wv >> 1, nh = wv & 1;
  const int nbase = nbh * 8 + nh * 4;         // first n-frag index of this wave
  const int kg = (lane >> 4) << 3;            // channel sub-offset 0/8/16/24

  int abase[2]; bool lastY[2], lastX[2];
  #pragma unroll
  for (int mf = 0; mf < 2; ++mf) {
    int pm = bm * 64 + mh * 32 + mf * 16 + (lane & 15);
    int pc = pm < P ? pm : P - 1;
    int oy = pc / OW, ox = pc % OW;
    lastY[mf] = (oy == OH - 1);
    lastX[mf] = (ox == OW - 1);
    abase[mf] = ((n * IH + 2 * oy) * IW + 2 * ox) * C + kg;
  }

  const f32x4 fz = {0.f, 0.f, 0.f, 0.f};
  f32x4 acc[2][4];
  #pragma unroll
  for (int mf = 0; mf < 2; ++mf)
    #pragma unroll
    for (int nf = 0; nf < 4; ++nf) acc[mf][nf] = fz;
  const bf16x8 bz = {0, 0, 0, 0, 0, 0, 0, 0};

  for (int tap = 0; tap < 9; ++tap) {
    const int r = tap / 3, s = tap - 3 * r;
    int aoff[2]; bool z[2];
    #pragma unroll
    for (int mf = 0; mf < 2; ++mf) {
      z[mf] = (r == 2 && lastY[mf]) || (s == 2 && lastX[mf]);
      aoff[mf] = abase[mf] + (r * IW + s) * C;
    }
    for (int cb = 0; cb < CB; ++cb) {
      bf16x8 a[2];
      #pragma unroll
      for (int mf = 0; mf < 2; ++mf) {
        if (!z[mf]) a[mf] = *(const bf16x8*)(in + aoff[mf] + cb * 32);
        else a[mf] = bz;
      }
      const u16* bp = pw + ((size_t)((tap * CB + cb) * NB + nbase)) * 512 + lane * 8;
      #pragma unroll
      for (int nf = 0; nf < 4; ++nf) {
        bf16x8 b = *(const bf16x8*)(bp + nf * 512);
        acc[0][nf] = __builtin_amdgcn_mfma_f32_16x16x32_bf16(a[0], b, acc[0][nf], 0, 0, 0);
        acc[1][nf] = __builtin_amdgcn_mfma_f32_16x16x32_bf16(a[1], b, acc[1][nf], 0, 0, 0);
      }
    }
  }

  // Epilogue: D col=lane&15 (outch), row=(lane>>4)*4+reg (pixel)
  const int rowg = (lane >> 4) << 2;
  #pragma unroll
  for (int mf = 0; mf < 2; ++mf)
    #pragma unroll
    for (int nf = 0; nf < 4; ++nf) {
      const int ch = (nbase + nf) * 16 + (lane & 15);
      const float bv = bias[ch];
      #pragma unroll
      for (int rr = 0; rr < 4; ++rr) {
        const int pix = bm * 64 + mh * 32 + mf * 16 + rowg + rr;
        if (pix < P)
          out[((size_t)n * P + pix) * K + ch] = f2bf(fmaxf(acc[mf][nf][rr] + bv, 0.f));
      }
    }
}

// ---------------------------------------------------------------------------
// Global avg pool over 196 pixels, bf16 NHWC [nb][196][512] -> feats fp32.
// Block per image; thread t handles channels 2t, 2t+1 (coalesced uint loads).
// ---------------------------------------------------------------------------
__global__ __launch_bounds__(256) void avgpool_nhwc(
    const u16* __restrict__ in, float* __restrict__ feats, int n0) {
  const int n = blockIdx.x, t = threadIdx.x;
  const u16* p = in + (size_t)n * 196 * 512 + t * 2;
  float s0 = 0.f, s1 = 0.f;
  for (int i = 0; i < 196; ++i) {
    unsigned u = *(const unsigned*)(p + (size_t)i * 512);
    s0 += bflo(u);
    s1 += bfhi(u);
  }
  float* f = feats + (size_t)(n0 + n) * 1024;
  f[2 * t] = s0 * (1.f / 196.f);
  f[2 * t + 1] = s1 * (1.f / 196.f);
}

// ---------------------------------------------------------------------------
// Text branch: masked mean of embedding rows. One block per batch row.
// ---------------------------------------------------------------------------
__global__ __launch_bounds__(256) void embed_mean_kernel(
    const int* __restrict__ seq, const int* __restrict__ len,
    const float* __restrict__ emb, float* __restrict__ means) {
  const int b = blockIdx.x;
  const int L = len[b];
  const int d = threadIdx.x;
  float a0 = 0.f, a1 = 0.f;
  for (int s = 0; s < L; ++s) {
    const float* e = emb + (size_t)seq[b * 128 + s] * 512;
    a0 += e[d];
    a1 += e[d + 256];
  }
  const float inv = 1.f / (float)L;
  means[b * 512 + d] = a0 * inv;
  means[b * 512 + d + 256] = a1 * inv;
}

// ---------------------------------------------------------------------------
// Small FC (fp32): out[m][col] = act(x[m] . W[:,col] + b[col]), W [K][N].
// ---------------------------------------------------------------------------
template<int K, int N, bool RELU>
__global__ __launch_bounds__(256) void fc_kernel(
    const float* __restrict__ x, int ldx,
    const float* __restrict__ w, const float* __restrict__ bias,
    float* __restrict__ out, int ldo) {
  __shared__ float row[K];
  const int m = blockIdx.y;
  for (int i = threadIdx.x; i < K; i += 256) row[i] = x[(size_t)m * ldx + i];
  __syncthreads();
  const int col = blockIdx.x * 256 + threadIdx.x;
  if (col < N) {
    float a = bias[col];
    for (int k = 0; k < K; ++k) a = fmaf(row[k], w[(size_t)k * N + col], a);
    out[(size_t)m * ldo + col] = RELU ? fmaxf(a, 0.f) : a;
  }
}

// ---------------------------------------------------------------------------
extern "C" void kernel_launch(void* const* d_in, const int* in_sizes, int n_in,
                              void* d_out, int out_size, void* d_ws, size_t ws_size,
                              hipStream_t stream) {
  const float* images = (const float*)d_in[0];
  const int*   seq    = (const int*)d_in[1];
  const int*   len    = (const int*)d_in[2];
  const float* emb    = (const float*)d_in[4];
  const float* cw1 = (const float*)d_in[5];  const float* cb1 = (const float*)d_in[6];
  const float* cw2 = (const float*)d_in[7];  const float* cb2 = (const float*)d_in[8];
  const float* cw3 = (const float*)d_in[9];  const float* cb3 = (const float*)d_in[10];
  const float* cw4 = (const float*)d_in[11]; const float* cb4 = (const float*)d_in[12];
  const float* rnn_w = (const float*)d_in[13]; const float* rnn_b = (const float*)d_in[14];
  const float* fc1_w = (const float*)d_in[15]; const float* fc1_b = (const float*)d_in[16];
  const float* fc2_w = (const float*)d_in[17]; const float* fc2_b = (const float*)d_in[18];
  const float* clf_w = (const float*)d_in[19]; const float* clf_b = (const float*)d_in[20];
  float* out = (float*)d_out;

  // ws layout (bytes): [bufA bf16][bufB bf16][pw2][pw3][pw4][means|feats|h1|h2 f32]
  const size_t A_E = (size_t)112 * 112 * 64;   // conv1 out elems/img (also holds conv3 out)
  const size_t B_E = (size_t)56 * 56 * 128;    // conv2 out elems/img (also holds conv4 out)
  const size_t PW2_E = 9 * 64 * 128, PW3_E = 9 * 128 * 256, PW4_E = 9 * 256 * 512;
  const size_t PER_IMG = (A_E + B_E) * 2;
  const size_t FIXED = (PW2_E + PW3_E + PW4_E) * 2 +
                       (size_t)(64 * 512 + 64 * 1024 + 64 * 512 + 64 * 512) * 4;
  int chunk = 64;
  if (ws_size < FIXED + 64 * PER_IMG) {
    size_t avail = (ws_size > FIXED) ? (ws_size - FIXED) : 0;
    size_t c = avail / PER_IMG;
    chunk = (c < 1) ? 1 : (c > 64 ? 64 : (int)c);
  }
  u16* bufA = (u16*)d_ws;
  u16* bufB = bufA + (size_t)chunk * A_E;
  u16* pw2 = bufB + (size_t)chunk * B_E;
  u16* pw3 = pw2 + PW2_E;
  u16* pw4 = pw3 + PW3_E;
  float* means = (float*)(pw4 + PW4_E);
  float* feats = means + 64 * 512;
  float* h1 = feats + 64 * 1024;
  float* h2 = h1 + 64 * 512;

  // weight repack (tiny)
  pack_w<64, 128><<<(9 * 64 * 128 + 255) / 256, 256, 0, stream>>>(cw2, pw2);
  pack_w<128, 256><<<(9 * 128 * 256 + 255) / 256, 256, 0, stream>>>(cw3, pw3);
  pack_w<256, 512><<<(9 * 256 * 512 + 255) / 256, 256, 0, stream>>>(cw4, pw4);

  // text branch
  embed_mean_kernel<<<64, 256, 0, stream>>>(seq, len, emb, means);
  fc_kernel<512, 512, false><<<dim3(2, 64), 256, 0, stream>>>(
      means, 512, rnn_w, rnn_b, feats + 512, 1024);

  // image branch
  for (int n0 = 0; n0 < 64; n0 += chunk) {
    int nb = 64 - n0; if (nb > chunk) nb = chunk;
    conv1_s2<<<dim3(49, nb), 256, 0, stream>>>(
        images + (size_t)n0 * 3 * 224 * 224, cw1, cb1, bufA);
    conv3x3s2_mfma<64, 128, 56, 56><<<dim3(49 * nb, 1), 256, 0, stream>>>(
        bufA, pw2, cb2, bufB);
    conv3x3s2_mfma<128, 256, 28, 28><<<dim3(13 * nb, 2), 256, 0, stream>>>(
        bufB, pw3, cb3, bufA);
    conv3x3s2_mfma<256, 512, 14, 14><<<dim3(4 * nb, 4), 256, 0, stream>>>(
        bufA, pw4, cb4, bufB);
    avgpool_nhwc<<<nb, 256, 0, stream>>>(bufB, feats, n0);
  }

  // head
  fc_kernel<1024, 512, true ><<<dim3(2, 64), 256, 0, stream>>>(feats, 1024, fc1_w, fc1_b, h1, 512);
  fc_kernel<512,  512, true ><<<dim3(2, 64), 256, 0, stream>>>(h1,    512,  fc2_w, fc2_b, h2, 512);
  fc_kernel<512, 1000, false><<<dim3(4, 64), 256, 0, stream>>>(h2,    512,  clf_w, clf_b, out, 1000);
}